// Round 1
// baseline (114.745 us; speedup 1.0000x reference)
//
#include <hip/hip_runtime.h>
#include <stdint.h>

typedef __bf16 bf16;
typedef __bf16 bf16x4 __attribute__((ext_vector_type(4)));
typedef __bf16 bf16x8 __attribute__((ext_vector_type(8)));
typedef float f32x16 __attribute__((ext_vector_type(16)));

#define BDIM 8192
#define DDIM 128
#define LDW 68   // LDS row stride in bf16 for a 64-wide K chunk (64 + 4 pad -> 2-way, free)

__device__ __forceinline__ uint32_t f2bf1(float f) {
    uint32_t u = __float_as_uint(f);
    return (u + 0x7FFFu + ((u >> 16) & 1u)) >> 16;   // RNE
}

// Convert fp32 [8192,128] -> bf16 (packed as uint), and fp32 row sum-of-squares.
// grid (2048, 2): y=0 -> output/xx, y=1 -> target/yy. One wave per row.
__global__ __launch_bounds__(256) void prep_kernel(const float* __restrict__ out_f,
                                                   const float* __restrict__ tgt_f,
                                                   uint32_t* __restrict__ ab,
                                                   float* __restrict__ xxyy) {
    const float* src = blockIdx.y ? tgt_f : out_f;
    uint32_t* dst = ab + (size_t)blockIdx.y * (BDIM * DDIM / 2);
    float* nrm = xxyy + (size_t)blockIdx.y * BDIM;

    int wid = threadIdx.x >> 6;
    int lane = threadIdx.x & 63;
    int row = blockIdx.x * 4 + wid;

    const float2* s = (const float2*)(src + (size_t)row * DDIM);
    float2 v = s[lane];                       // cols 2*lane, 2*lane+1 (64 lanes * 2 = 128)
    dst[row * (DDIM / 2) + lane] = f2bf1(v.x) | (f2bf1(v.y) << 16);

    float sq = v.x * v.x + v.y * v.y;
    #pragma unroll
    for (int off = 32; off > 0; off >>= 1) sq += __shfl_down(sq, off);
    if (lane == 0) nrm[row] = sq;
}

// 128x128 tile per block; C = A_bf16 * B_bf16^T via mfma 32x32x16;
// fused d = sqrt(max(xx+yy-2c,0)) with diag sign; per-block partial sum out.
__global__ __launch_bounds__(256) void dist_kernel(const uint32_t* __restrict__ Ag,
                                                   const uint32_t* __restrict__ Bg,
                                                   const float* __restrict__ xxg,
                                                   const float* __restrict__ yyg,
                                                   float* __restrict__ partials) {
    __shared__ bf16 Al[128 * LDW];
    __shared__ bf16 Bl[128 * LDW];
    __shared__ float xxl[128];
    __shared__ float yyl[128];
    __shared__ float wsum[4];

    const int tid = threadIdx.x;
    const int lane = tid & 63;
    const int wid = tid >> 6;
    const int wr = wid >> 1, wc = wid & 1;      // 2x2 wave grid, each wave 64x64
    const int bx = blockIdx.x, by = blockIdx.y;

    if (tid < 128) xxl[tid] = xxg[bx * 128 + tid];
    else           yyl[tid - 128] = yyg[by * 128 + (tid - 128)];

    // Each tile is 128 full rows of the source matrix (K = full row of 128 bf16).
    const uint2* Ga = (const uint2*)Ag + (size_t)bx * 128 * 32;  // 32 uint2 per row
    const uint2* Gb = (const uint2*)Bg + (size_t)by * 128 * 32;

    f32x16 acc[2][2] = {};

    #pragma unroll
    for (int ch = 0; ch < 2; ++ch) {            // two K-chunks of 64
        if (ch) __syncthreads();                // compute on prev chunk done
        const int ck = ch * 16;                 // uint2 offset within a row
        #pragma unroll
        for (int i = 0; i < 8; ++i) {           // 2048 8B-segments per matrix chunk
            int idx = tid + i * 256;
            int r = idx >> 4, sseg = idx & 15;
            uint2 va = Ga[r * 32 + ck + sseg];
            uint2 vb = Gb[r * 32 + ck + sseg];
            *(uint2*)&Al[r * LDW + sseg * 4] = va;
            *(uint2*)&Bl[r * LDW + sseg * 4] = vb;
        }
        __syncthreads();

        #pragma unroll
        for (int k0 = 0; k0 < 64; k0 += 16) {
            const int kk = k0 + ((lane >> 5) << 3);   // A[m][k=(lane>>5)*8+j]
            bf16x8 af[2], bfr[2];
            #pragma unroll
            for (int t = 0; t < 2; ++t) {
                int am = wr * 64 + t * 32 + (lane & 31);
                bf16x4 lo = *(const bf16x4*)&Al[am * LDW + kk];
                bf16x4 hi = *(const bf16x4*)&Al[am * LDW + kk + 4];
                af[t] = __builtin_shufflevector(lo, hi, 0, 1, 2, 3, 4, 5, 6, 7);
                int bn = wc * 64 + t * 32 + (lane & 31);
                bf16x4 lo2 = *(const bf16x4*)&Bl[bn * LDW + kk];
                bf16x4 hi2 = *(const bf16x4*)&Bl[bn * LDW + kk + 4];
                bfr[t] = __builtin_shufflevector(lo2, hi2, 0, 1, 2, 3, 4, 5, 6, 7);
            }
            acc[0][0] = __builtin_amdgcn_mfma_f32_32x32x16_bf16(af[0], bfr[0], acc[0][0], 0, 0, 0);
            acc[0][1] = __builtin_amdgcn_mfma_f32_32x32x16_bf16(af[0], bfr[1], acc[0][1], 0, 0, 0);
            acc[1][0] = __builtin_amdgcn_mfma_f32_32x32x16_bf16(af[1], bfr[0], acc[1][0], 0, 0, 0);
            acc[1][1] = __builtin_amdgcn_mfma_f32_32x32x16_bf16(af[1], bfr[1], acc[1][1], 0, 0, 0);
        }
    }

    // Epilogue: d = sqrt(max(xx+yy-2c, 0)); diag weight -1, off-diag +1.
    float s = 0.0f;
    const bool diagBlock = (bx == by);
    #pragma unroll
    for (int tr = 0; tr < 2; ++tr) {
        float xv[16];
        #pragma unroll
        for (int r = 0; r < 16; ++r) {
            int ml = wr * 64 + tr * 32 + (r & 3) + 8 * (r >> 2) + 4 * (lane >> 5);
            xv[r] = xxl[ml];
        }
        #pragma unroll
        for (int tc = 0; tc < 2; ++tc) {
            int nl = wc * 64 + tc * 32 + (lane & 31);
            float yv = yyl[nl];
            #pragma unroll
            for (int r = 0; r < 16; ++r) {
                float c = acc[tr][tc][r];
                float d2 = fmaf(-2.0f, c, xv[r] + yv);
                float d = sqrtf(fmaxf(d2, 0.0f));
                int ml = wr * 64 + tr * 32 + (r & 3) + 8 * (r >> 2) + 4 * (lane >> 5);
                bool diag = diagBlock && (ml == nl);
                s += diag ? -d : d;
            }
        }
    }
    #pragma unroll
    for (int off = 32; off > 0; off >>= 1) s += __shfl_down(s, off);
    if (lane == 0) wsum[wid] = s;
    __syncthreads();
    if (tid == 0) partials[by * 64 + bx] = wsum[0] + wsum[1] + wsum[2] + wsum[3];
}

__global__ __launch_bounds__(256) void reduce_kernel(const float* __restrict__ partials,
                                                     float* __restrict__ out) {
    __shared__ float wsum[4];
    float s = 0.0f;
    for (int i = threadIdx.x; i < 4096; i += 256) s += partials[i];
    #pragma unroll
    for (int off = 32; off > 0; off >>= 1) s += __shfl_down(s, off);
    int lane = threadIdx.x & 63, wid = threadIdx.x >> 6;
    if (lane == 0) wsum[wid] = s;
    __syncthreads();
    if (threadIdx.x == 0)
        out[0] = (wsum[0] + wsum[1] + wsum[2] + wsum[3]) * (0.1f / 8192.0f);
}

extern "C" void kernel_launch(void* const* d_in, const int* in_sizes, int n_in,
                              void* d_out, int out_size, void* d_ws, size_t ws_size,
                              hipStream_t stream) {
    const float* output = (const float*)d_in[0];
    const float* target = (const float*)d_in[1];

    uint8_t* ws = (uint8_t*)d_ws;
    uint32_t* ab      = (uint32_t*)ws;                              // A bf16 (2MB) + B bf16 (2MB)
    float*    xxyy    = (float*)(ws + 4u * 1024u * 1024u);          // xx (32KB) + yy (32KB)
    float*    partial = (float*)(ws + 4u * 1024u * 1024u + 64u * 1024u); // 4096 floats

    prep_kernel<<<dim3(2048, 2), 256, 0, stream>>>(output, target, ab, xxyy);
    dist_kernel<<<dim3(64, 64), 256, 0, stream>>>(ab, ab + (BDIM * DDIM / 2),
                                                  xxyy, xxyy + BDIM, partial);
    reduce_kernel<<<1, 256, 0, stream>>>(partial, (float*)d_out);
}